// Round 7
// baseline (3515.133 us; speedup 1.0000x reference)
//
#include <hip/hip_runtime.h>
#include <stdint.h>

#define Tn 100
#define Dn 51
#define Hn 128
#define G4 512     // 4*H
#define BR 8       // batch rows per workgroup
#define NWG 256    // workgroups (2048 / 8) = 1 WG/CU
#define NTH 1024   // 16 waves, 4/SIMD
#define RP 264     // xhA row stride in bf16 elems (16B-aligned rows)

typedef unsigned int uint32;
typedef unsigned short u16;
typedef short s16x8 __attribute__((ext_vector_type(8)));   // 8 bf16 = 4 VGPRs
typedef float f32x4v __attribute__((ext_vector_type(4)));

__device__ __forceinline__ float rcp_(float x){ return __builtin_amdgcn_rcpf(x); }
__device__ __forceinline__ float sigm(float x){ return rcp_(1.f + __expf(-x)); }
__device__ __forceinline__ float tanh_(float x){ return 1.f - 2.f*rcp_(1.f + __expf(2.f*x)); }

// fp32 -> bf16 round-to-nearest-even
__device__ __forceinline__ u16 f2bf(float f){
  uint32 u = __float_as_uint(f);
  return (u16)((u + 0x7fffu + ((u >> 16) & 1u)) >> 16);
}
__device__ __forceinline__ float bf2f(u16 u){ return __uint_as_float(((uint32)u)<<16); }

// A-fragment trick: row r (0..7) = bf16-hi of xh row r; row r+8 = bf16-lo.
// One MFMA computes both pumps; epilogue sums D[r] + D[r+8] via shfl.
__device__ __forceinline__ void wr_xh(u16* __restrict__ xhA, int r, int k, float v){
  u16 h = f2bf(v);
  xhA[r*RP + k]     = h;
  xhA[(r+8)*RP + k] = f2bf(v - bf2f(h));
}

struct WP {
  const float* W[6];   // [4H, din]  enc0..2, dec0..2 (fp32)
  const float* U[6];   // [4H, H]
  const float* Bb[6];  // [4H]
  const float* fW;     // [D, H]
  const float* fb;     // [D]
};

// ws: wsw = MFMA-B-fragment-swizzled bf16 weights.
// Layout per layer (uniform 131072 u16): chunk (n,s) at ((n*8+s)*64+lane)*8+j,
// holding Wc[k = s*32+(lane>>4)*8+j][c = n*16+(lane&15)], Wc = [Wih | Whh] along k,
// zero-padded (k>=K or s>=S). A wave's B-frag load = contiguous 1KB dwordx4.
// fwt: [128][64] f32 (k-major, d minor, d>=51 pad 0) -- proj reads 64 consecutive
// floats per k across 64 lanes = conflict-free.
#define PREP_TOTAL (6*131072 + 6*512 + 8192 + 64)
__global__ void prep_kernel(WP p, u16* __restrict__ wsw, float* __restrict__ bias,
                            float* __restrict__ fwt, float* __restrict__ fbw)
{
  int gid = blockIdx.x*256 + threadIdx.x;
  if (gid >= PREP_TOTAL) return;
  if (gid < 6*131072){
    int l = gid >> 17;
    int e = gid & 131071;
    int n    = e >> 12;
    int s    = (e >> 9) & 7;
    int lane = (e >> 3) & 63;
    int j    = e & 7;
    int k = s*32 + (lane >> 4)*8 + j;
    int c = n*16 + (lane & 15);
    int din = (l % 3 == 0) ? Dn : Hn;
    int K = din + Hn;
    u16 v = 0;
    if (k < K){
      float f = (k < din) ? p.W[l][(size_t)c*din + k] : p.U[l][(size_t)c*Hn + (k - din)];
      v = f2bf(f);
    }
    wsw[gid] = v;
  } else if (gid < 6*131072 + 6*512){
    int i = gid - 6*131072;
    bias[i] = p.Bb[i>>9][i & 511];
  } else if (gid < 6*131072 + 6*512 + 8192){
    int i = gid - (6*131072 + 6*512);
    int k = i >> 6, d = i & 63;
    fwt[i] = (d < Dn) ? p.fW[(size_t)d*Hn + k] : 0.f;
  } else {
    int d = gid - (6*131072 + 6*512 + 8192);
    fbw[d] = (d < Dn) ? p.fb[d] : 0.f;
  }
}

// LDS-only barrier: drains DS ops (each wave's own reads/writes), NOT vmcnt.
// Cheap: avoids pointless drains of the src prefetch crossing phase bounds.
// All cross-thread data in this kernel lives in LDS; 'out' is never read back.
__device__ __forceinline__ void bar_lds(){
  asm volatile("s_waitcnt lgkmcnt(0)" ::: "memory");
  __builtin_amdgcn_s_barrier();
}

// gates[r][c] = bias[c] + sum_k xh[r][k]*Wc[k][c] via mfma_f32_16x16x32_bf16.
// Wave w owns N-tiles n0=2w, 2w+1.
// R6 post-mortem: the DMA-ring (counted-vmcnt LDS ring) was falsified at both
// 8 and 16 waves (FETCH blew up 35x, per-sub-phase latency exposure). This
// round instead pays the B-weight L2 latency ONCE per gemm: ALL S*2 B-frags
// are issued as independent global loads into registers up front (64 VGPRs,
// compile-time-indexed arrays), sched_barrier(0) pins the cluster, then the
// MFMA loop consumes them (compiler inserts counted vmcnt per use). R2's
// unroll-2 paid ~250cy of exposed L2 latency 4x per gemm<8>; this pays it ~1x.
// VGPR budget is DELIBERATE (R11 lesson): B 64 + acc 8 + misc ~40 ≈ 110 < 128.
// C/D: col=lane&15, row=(lane>>4)*4+reg (m89) -> row r in lanes 0-31, r+8 in 32-63.
template<int S>
__device__ __forceinline__ void gemm_stage(const u16* __restrict__ wsl,
                                           float bv0, float bv1,
                                           const u16* __restrict__ xh_in,
                                           float* __restrict__ gates,
                                           int wave, int lane)
{
  const int mrow = lane & 15, kgrp = lane >> 4;
  const int n0 = wave*2;
  const u16* bp0 = wsl + n0*4096 + lane*8;
  const int aoff = mrow*RP + (kgrp << 3);
  s16x8 B0[S], B1[S];
  #pragma unroll
  for (int s=0; s<S; s++){
    B0[s] = *(const s16x8*)(bp0 + s*512);
    B1[s] = *(const s16x8*)(bp0 + 4096 + s*512);
  }
  __builtin_amdgcn_sched_barrier(0);   // keep the 2S loads clustered ahead of MFMAs
  f32x4v acc0 = {0.f,0.f,0.f,0.f}, acc1 = {0.f,0.f,0.f,0.f};
  #pragma unroll
  for (int s=0; s<S; s++){
    s16x8 a = *(const s16x8*)(xh_in + aoff + s*32);
    acc0 = __builtin_amdgcn_mfma_f32_16x16x32_bf16(a, B0[s], acc0, 0, 0, 0);
    acc1 = __builtin_amdgcn_mfma_f32_16x16x32_bf16(a, B1[s], acc1, 0, 0, 0);
  }
  // fold lo-product rows (A rows 8-15, lanes 32-63) into hi rows (lanes 0-31)
  #pragma unroll
  for (int v=0; v<4; v++){
    float l0 = __shfl_down(acc0[v], 32);
    float l1 = __shfl_down(acc1[v], 32);
    acc0[v] += l0;
    acc1[v] += l1;
  }
  if (kgrp < 2){
    int rb = kgrp*4;
    int c0g = n0*16 + mrow, c1g = c0g + 16;
    #pragma unroll
    for (int v=0; v<4; v++){
      gates[(rb+v)*G4 + c0g] = acc0[v] + bv0;
      gates[(rb+v)*G4 + c1g] = acc1[v] + bv1;
    }
  }
}

// Fused activation: gates -> (h, c-in-REGISTER), h written straight into the
// A-tiles that consume it. Thread->(r,j) map is static across the kernel, so
// c-state is one VGPR per layer per thread (no cS LDS traffic).
__device__ __forceinline__ void activate2(const float* __restrict__ gates, float& cref,
                                          u16* __restrict__ xh_self, int din_self,
                                          u16* __restrict__ xh_next,
                                          float* __restrict__ h2S, int tid)
{
  int r = tid >> 7, j = tid & 127;       // 1024 threads = 8 rows x 128
  const float* g = gates + r*G4;
  float ig = sigm (g[j]);
  float fg = sigm (g[j + Hn]);
  float gg = tanh_(g[j + 2*Hn]);
  float og = sigm (g[j + 3*Hn]);
  cref = fg*cref + ig*gg;
  float hv = og*tanh_(cref);
  wr_xh(xh_self, r, din_self + j, hv);
  if (xh_next) wr_xh(xh_next, r, j, hv);
  if (h2S)     h2S[r*Hn + j] = hv;
}

// OUTPUT IS FP32. 8 rows x 64 cols = 512 work items; fwtS[k*64+d] reads are
// 64-consecutive-float per k = conflict-free. pred feeds xh0.x directly.
__device__ __forceinline__ void proj_out(const float* __restrict__ h2S,
                                         const float* __restrict__ fwtS,
                                         const float* __restrict__ fbwS,
                                         u16* __restrict__ xh0,
                                         float* __restrict__ out, long b0, int t, int tid)
{
  if (tid < 512){
    int r = tid >> 6, d = tid & 63;
    const float* h = h2S + r*Hn;
    float acc = 0.f;
    #pragma unroll 8
    for (int k=0;k<Hn;k++) acc += h[k] * fwtS[k*64 + d];
    if (d < Dn){
      float pv = acc + fbwS[d];
      out[((size_t)(b0+r)*Tn + (Tn-1-t))*Dn + d] = pv;
      wr_xh(xh0, r, d, pv);
    }
  }
}

// (1024, 4): 4 waves/EU -> VGPR cap 128 (R9/R11: never let this spill;
// tripwire = VGPR_Count 128 + FETCH >> 100 MB).
__global__ __launch_bounds__(NTH, 4) void lstm_kernel(
    const float* __restrict__ src, const u16* __restrict__ wsw,
    const float* __restrict__ bias, const float* __restrict__ fwt,
    const float* __restrict__ fbw, float* __restrict__ out)
{
  __shared__ __align__(16) u16   xhA[3*16*RP];    // 24.75 KB per-layer A-tiles
  __shared__ __align__(16) float gates[BR*G4];    // 16 KB
  __shared__ __align__(16) float fwtS[8192];      // 32 KB f32 (accuracy: keep f32)
  __shared__ __align__(16) float h2S[BR*Hn];      // 4 KB dec-l2 h for proj
  __shared__ __align__(16) float fbwS[64];        // 0.25 KB   (total ~77 KB)

  const int tid = threadIdx.x;
  const int wave = tid >> 6, lane = tid & 63;
  const long b0 = (long)blockIdx.x * BR;
  u16* xh0 = xhA;
  u16* xh1 = xhA + 16*RP;
  u16* xh2 = xhA + 32*RP;

  const u16* wsE0 = wsw;
  const u16* wsE1 = wsw + 1*131072;
  const u16* wsE2 = wsw + 2*131072;
  const u16* wsD0 = wsw + 3*131072;
  const u16* wsD1 = wsw + 4*131072;
  const u16* wsD2 = wsw + 5*131072;

  // persistent per-thread state: c for 3 layers (act mapping r=tid>>7,j=tid&127)
  float c0 = 0.f, c1 = 0.f, c2 = 0.f;
  // per-thread epilogue biases for columns c0g, c0g+16, all 6 layers (12 VGPRs)
  const int c0g = wave*32 + (lane & 15);
  #define LB(l,o) bias[(l)*G4 + c0g + (o)]
  float bE0a=LB(0,0), bE0b=LB(0,16), bE1a=LB(1,0), bE1b=LB(1,16);
  float bE2a=LB(2,0), bE2b=LB(2,16), bD0a=LB(3,0), bD0b=LB(3,16);
  float bD1a=LB(4,0), bD1b=LB(4,16), bD2a=LB(5,0), bD2b=LB(5,16);
  #undef LB

  // src(0) prefetch
  float sA = 0.f, sB = 0.f;
  { int kk = tid & 255;
    if (kk < Dn){ int r0 = tid >> 8;
      sA = src[((size_t)(b0+r0)*Tn + 0)*Dn + kk];
      sB = src[((size_t)(b0+r0+4)*Tn + 0)*Dn + kk]; } }

  // ---- init LDS ----
  for (int i=tid; i<8192; i+=NTH) fwtS[i] = fwt[i];
  if (tid < 64) fbwS[tid] = fbw[tid];
  for (int i=tid; i<3*16*RP; i+=NTH) xhA[i] = 0;   // pads stay 0 forever
  __syncthreads();
  { int kk = tid & 255;
    if (kk < Dn){ int r0 = tid >> 8;
      wr_xh(xh0, r0,   kk, sA);
      wr_xh(xh0, r0+4, kk, sB); } }                // src(0) -> xh0.x
  __syncthreads();

  // ---------------- encoder: 6 lgkm-barriers per t ----------------
  for (int t=0;t<Tn;t++){
    int tn = (t < Tn-1) ? t+1 : Tn-1;
    { int kk = tid & 255;                          // src(t+1) -> regs
      if (kk < Dn){ int r0 = tid >> 8;
        sA = src[((size_t)(b0+r0)*Tn + tn)*Dn + kk];
        sB = src[((size_t)(b0+r0+4)*Tn + tn)*Dn + kk]; } }
    gemm_stage<6>(wsE0, bE0a, bE0b, xh0, gates, wave, lane);
    bar_lds();
    activate2(gates, c0, xh0, Dn, xh1, nullptr, tid);
    if (t < Tn-1){ int kk = tid & 255;             // xh0.x idle during act-l0
      if (kk < Dn){ int r0 = tid >> 8;
        wr_xh(xh0, r0,   kk, sA);
        wr_xh(xh0, r0+4, kk, sB); } }
    bar_lds();

    gemm_stage<8>(wsE1, bE1a, bE1b, xh1, gates, wave, lane);
    bar_lds();
    activate2(gates, c1, xh1, Hn, xh2, nullptr, tid);
    bar_lds();

    gemm_stage<8>(wsE2, bE2a, bE2b, xh2, gates, wave, lane);
    bar_lds();
    activate2(gates, c2, xh2, Hn, nullptr, nullptr, tid);
    bar_lds();
  }

  // ---------------- decoder ----------------
  // xh*.h-parts + c regs carry enc-final state. Reset xh0.x to pred(-1)=0.
  { int r = tid >> 7, kk = tid & 127;
    if (kk < Dn){ xh0[r*RP + kk] = 0; xh0[(r+8)*RP + kk] = 0; } }
  bar_lds();

  for (int t=0;t<Tn;t++){
    gemm_stage<6>(wsD0, bD0a, bD0b, xh0, gates, wave, lane);
    bar_lds();
    activate2(gates, c0, xh0, Dn, xh1, nullptr, tid);
    bar_lds();

    gemm_stage<8>(wsD1, bD1a, bD1b, xh1, gates, wave, lane);
    bar_lds();
    activate2(gates, c1, xh1, Hn, xh2, nullptr, tid);
    bar_lds();

    gemm_stage<8>(wsD2, bD2a, bD2b, xh2, gates, wave, lane);
    bar_lds();
    activate2(gates, c2, xh2, Hn, nullptr, h2S, tid);
    bar_lds();

    proj_out(h2S, fwtS, fbwS, xh0, out, b0, t, tid);
    bar_lds();
  }
}

extern "C" void kernel_launch(void* const* d_in, const int* in_sizes, int n_in,
                              void* d_out, int out_size, void* d_ws, size_t ws_size,
                              hipStream_t stream)
{
  (void)in_sizes; (void)n_in; (void)out_size; (void)ws_size;
  const float* src = (const float*)d_in[0];
  WP p;
  for (int l=0;l<3;l++){
    p.W[l]    = (const float*)d_in[1  + 3*l];
    p.U[l]    = (const float*)d_in[2  + 3*l];
    p.Bb[l]   = (const float*)d_in[3  + 3*l];
    p.W[3+l]  = (const float*)d_in[10 + 3*l];
    p.U[3+l]  = (const float*)d_in[11 + 3*l];
    p.Bb[3+l] = (const float*)d_in[12 + 3*l];
  }
  p.fW = (const float*)d_in[19];
  p.fb = (const float*)d_in[20];

  // ws: wsw u16[786432] (1.5MB) | bias f32[3072] | fwt f32[8192] | fbw f32[64]
  u16*   wsw  = (u16*)d_ws;
  float* bias = (float*)((char*)d_ws + 6*131072*sizeof(u16));
  float* fwt  = bias + 6*512;
  float* fbw  = fwt + 8192;

  prep_kernel<<<(PREP_TOTAL + 255)/256, 256, 0, stream>>>(p, wsw, bias, fwt, fbw);
  lstm_kernel<<<NWG, NTH, 0, stream>>>(src, wsw, bias, fwt, fbw, (float*)d_out);
}

// Round 8
// 2068.971 us; speedup vs baseline: 1.6990x; 1.6990x over previous
//
#include <hip/hip_runtime.h>
#include <stdint.h>

#define Tn 100
#define Dn 51
#define Hn 128
#define G4 512     // 4*H
#define BR 8       // batch rows per workgroup
#define NWG 256    // workgroups (2048 / 8) = 1 WG/CU
#define NTH 1024   // 16 waves, 4/SIMD (proven R2 regime)
#define RP 264     // xhA row stride in bf16 elems (16B-aligned rows)

typedef unsigned int uint32;
typedef unsigned short u16;
typedef short s16x8 __attribute__((ext_vector_type(8)));   // 8 bf16 = 4 VGPRs
typedef float f32x4v __attribute__((ext_vector_type(4)));

__device__ __forceinline__ float rcp_(float x){ return __builtin_amdgcn_rcpf(x); }
__device__ __forceinline__ float sigm(float x){ return rcp_(1.f + __expf(-x)); }
__device__ __forceinline__ float tanh_(float x){ return 1.f - 2.f*rcp_(1.f + __expf(2.f*x)); }

// fp32 -> bf16 round-to-nearest-even
__device__ __forceinline__ u16 f2bf(float f){
  uint32 u = __float_as_uint(f);
  return (u16)((u + 0x7fffu + ((u >> 16) & 1u)) >> 16);
}
__device__ __forceinline__ float bf2f(u16 u){ return __uint_as_float(((uint32)u)<<16); }

// A-fragment trick: row r (0..7) = bf16-hi of xh row r; row r+8 = bf16-lo.
// One MFMA computes both pumps; epilogue sums D[r] + D[r+8] via shfl.
__device__ __forceinline__ void wr_xh(u16* __restrict__ xhA, int r, int k, float v){
  u16 h = f2bf(v);
  xhA[r*RP + k]     = h;
  xhA[(r+8)*RP + k] = f2bf(v - bf2f(h));
}

struct WP {
  const float* W[6];   // [4H, din]  enc0..2, dec0..2 (fp32)
  const float* U[6];   // [4H, H]
  const float* Bb[6];  // [4H]
  const float* fW;     // [D, H]
  const float* fb;     // [D]
};

// ws: wsw = MFMA-B-fragment-swizzled bf16 weights, GATE-INTERLEAVED columns.
// Permuted col c' = unit*4 + gate (gate 0..3 = i,f,g,o; actual col C =
// gate*128 + unit). Tile n holds units [4n,4n+4) x all 4 gates -> wave w
// (tiles 2w,2w+1) owns all gates of units [8w,8w+8): activation becomes a
// per-wave epilogue (4-lane transpose), no gates-LDS round-trip, half the
// barriers. Chunk (n,s) at ((n*8+s)*64+lane)*8+j holds
// Wc[k = s*32+(lane>>4)*8+j][c' = n*16+(lane&15)], Wc = [Wih | Whh] along k,
// zero-padded (k>=K). bias is stored in the SAME permuted order.
// fwt: [128][64] f32 (k-major, d minor, d>=51 pad 0) -- proj reads 64
// consecutive floats per k across 64 lanes = conflict-free.
#define PREP_TOTAL (6*131072 + 6*512 + 8192 + 64)
__global__ void prep_kernel(WP p, u16* __restrict__ wsw, float* __restrict__ bias,
                            float* __restrict__ fwt, float* __restrict__ fbw)
{
  int gid = blockIdx.x*256 + threadIdx.x;
  if (gid >= PREP_TOTAL) return;
  if (gid < 6*131072){
    int l = gid >> 17;
    int e = gid & 131071;
    int n    = e >> 12;
    int s    = (e >> 9) & 7;
    int lane = (e >> 3) & 63;
    int j    = e & 7;
    int k  = s*32 + (lane >> 4)*8 + j;
    int cp = n*16 + (lane & 15);           // permuted col
    int C  = (cp & 3)*128 + (cp >> 2);     // actual col: gate*128 + unit
    int din = (l % 3 == 0) ? Dn : Hn;
    int K = din + Hn;
    u16 v = 0;
    if (k < K){
      float f = (k < din) ? p.W[l][(size_t)C*din + k] : p.U[l][(size_t)C*Hn + (k - din)];
      v = f2bf(f);
    }
    wsw[gid] = v;
  } else if (gid < 6*131072 + 6*512){
    int i = gid - 6*131072;
    int l = i >> 9, cp = i & 511;
    bias[i] = p.Bb[l][(cp & 3)*128 + (cp >> 2)];   // permuted bias
  } else if (gid < 6*131072 + 6*512 + 8192){
    int i = gid - (6*131072 + 6*512);
    int k = i >> 6, d = i & 63;
    fwt[i] = (d < Dn) ? p.fW[(size_t)d*Hn + k] : 0.f;
  } else {
    int d = gid - (6*131072 + 6*512 + 8192);
    fbw[d] = (d < Dn) ? p.fb[d] : 0.f;
  }
}

// LDS-only barrier: drains DS ops, NOT vmcnt (src prefetch stays in flight).
// All cross-thread data in this kernel lives in LDS; 'out' is never read back.
__device__ __forceinline__ void bar_lds(){
  asm volatile("s_waitcnt lgkmcnt(0)" ::: "memory");
  __builtin_amdgcn_s_barrier();
}

// 4x4 butterfly transpose across lane groups of 4 (elements = acc rows).
// In: x[v] = col(this lane's gate) value for row v. Out on lane base+p:
// x[g] = gate g value for row p.  8 shfl_xor + selects, no LDS.
__device__ __forceinline__ void xpose4(f32x4v& x, int lane){
  float p0,p1,p2,p3;
  p0 = __shfl_xor(x[1], 1); p1 = __shfl_xor(x[0], 1);
  p2 = __shfl_xor(x[3], 1); p3 = __shfl_xor(x[2], 1);
  if (lane & 1){ x[0] = p0; x[2] = p2; } else { x[1] = p1; x[3] = p3; }
  p0 = __shfl_xor(x[2], 2); p1 = __shfl_xor(x[3], 2);
  p2 = __shfl_xor(x[0], 2); p3 = __shfl_xor(x[1], 2);
  if (lane & 2){ x[0] = p0; x[1] = p1; } else { x[2] = p2; x[3] = p3; }
}

// One FUSED layer-step: gemm (R2's proven unroll-2 loop, weights streamed
// global->VGPR in-phase -- R1/R7/R11 all showed hipcc spills past ~4 in-flight
// frags, so the 4-load window stays) + lo-fold + 4-lane transpose + in-wave
// activation. Gate-interleaved tiles mean wave w's acc holds all 4 gates of
// units 8w..8w+7; after xpose4, lane kgrp*16+u*4+p holds i,f,g,o of
// (row kgrp*4+p, units 8w+u / 8w+4+u). Bias rides in the hi-pump acc init
// (read from LDS, no bias VGPRs). c-state: 2 VGPRs/lane/layer.
// h-writes: xh_next BEFORE the barrier (nobody reads xh_{l+1} during phase l);
// xh_self AFTER it (other waves still gemm-read xh_l pre-barrier).
// C/D: col=lane&15, row=(lane>>4)*4+reg (m89) -> rows 0-7 in lanes 0-31 after fold.
template<int S, bool H2SW>
__device__ __forceinline__ void layer_fused(const u16* __restrict__ wsl,
                                            const float* __restrict__ biasL,
                                            const u16* __restrict__ xh_in,
                                            u16* __restrict__ xh_self, int din_self,
                                            u16* __restrict__ xh_next,
                                            float* __restrict__ h2S,
                                            float& cA, float& cB,
                                            int wave, int lane)
{
  const int mrow = lane & 15, kgrp = lane >> 4;
  const int n0 = wave*2;
  const u16* bp0 = wsl + n0*4096 + lane*8;
  const int aoff = mrow*RP + (kgrp << 3);
  const bool hi = (kgrp < 2);
  float bv0 = hi ? biasL[n0*16 + mrow]      : 0.f;   // LDS, broadcast-friendly
  float bv1 = hi ? biasL[n0*16 + 16 + mrow] : 0.f;
  f32x4v acc0 = {bv0,bv0,bv0,bv0}, acc1 = {bv1,bv1,bv1,bv1};
  #pragma unroll 2
  for (int s=0; s<S; s++){
    s16x8 a  = *(const s16x8*)(xh_in + aoff + s*32);
    s16x8 b0 = *(const s16x8*)(bp0 + s*512);
    s16x8 b1 = *(const s16x8*)(bp0 + 4096 + s*512);
    acc0 = __builtin_amdgcn_mfma_f32_16x16x32_bf16(a, b0, acc0, 0, 0, 0);
    acc1 = __builtin_amdgcn_mfma_f32_16x16x32_bf16(a, b1, acc1, 0, 0, 0);
  }
  // fold lo-product rows (A rows 8-15, lanes 32-63) into hi rows (lanes 0-31)
  #pragma unroll
  for (int v=0; v<4; v++){
    acc0[v] += __shfl_down(acc0[v], 32);
    acc1[v] += __shfl_down(acc1[v], 32);
  }
  // gate transpose (all lanes execute; results used only on lanes 0-31)
  xpose4(acc0, lane);
  xpose4(acc1, lane);
  const int r  = (kgrp << 2) + (lane & 3);         // batch row 0..7
  const int U0 = wave*8 + ((lane >> 2) & 3);       // unit of tile n0
  const int U1 = U0 + 4;                           // unit of tile n0+1
  float hv0 = 0.f, hv1 = 0.f;
  if (hi){
    float iv = sigm (acc0[0]);
    float fv = sigm (acc0[1]);
    float gv = tanh_(acc0[2]);
    float ov = sigm (acc0[3]);
    cA = fv*cA + iv*gv;
    hv0 = ov*tanh_(cA);
    iv = sigm (acc1[0]);
    fv = sigm (acc1[1]);
    gv = tanh_(acc1[2]);
    ov = sigm (acc1[3]);
    cB = fv*cB + iv*gv;
    hv1 = ov*tanh_(cB);
    if (xh_next){
      wr_xh(xh_next, r, U0, hv0);
      wr_xh(xh_next, r, U1, hv1);
    }
    if (H2SW){
      h2S[r*Hn + U0] = hv0;
      h2S[r*Hn + U1] = hv1;
    }
  }
  bar_lds();
  if (hi){
    wr_xh(xh_self, r, din_self + U0, hv0);
    wr_xh(xh_self, r, din_self + U1, hv1);
  }
}

// OUTPUT IS FP32. 8 rows x 64 cols = 512 work items; fwtS[k*64+d] reads are
// 64-consecutive-float per k = conflict-free. pred feeds xh0.x directly.
__device__ __forceinline__ void proj_out(const float* __restrict__ h2S,
                                         const float* __restrict__ fwtS,
                                         const float* __restrict__ fbwS,
                                         u16* __restrict__ xh0,
                                         float* __restrict__ out, long b0, int t, int tid)
{
  if (tid < 512){
    int r = tid >> 6, d = tid & 63;
    const float* h = h2S + r*Hn;
    float acc = 0.f;
    #pragma unroll 8
    for (int k=0;k<Hn;k++) acc += h[k] * fwtS[k*64 + d];
    if (d < Dn){
      float pv = acc + fbwS[d];
      out[((size_t)(b0+r)*Tn + (Tn-1-t))*Dn + d] = pv;
      wr_xh(xh0, r, d, pv);
    }
  }
}

// (1024, 4): 4 waves/EU. Tripwire (R1/R7/R11): VGPR_Count==64 AND FETCH>>100MB
// means the allocator spilled -> revert to R2. Expected ~55 VGPR here.
__global__ __launch_bounds__(NTH, 4) void lstm_kernel(
    const float* __restrict__ src, const u16* __restrict__ wsw,
    const float* __restrict__ bias, const float* __restrict__ fwt,
    const float* __restrict__ fbw, float* __restrict__ out)
{
  __shared__ __align__(16) u16   xhA[3*16*RP];    // 24.75 KB per-layer A-tiles
  __shared__ __align__(16) float fwtS[8192];      // 32 KB f32 (accuracy: keep f32)
  __shared__ __align__(16) float biasS[6*G4];     // 12 KB (permuted)
  __shared__ __align__(16) float h2S[BR*Hn];      // 4 KB dec-l2 h for proj
  __shared__ __align__(16) float fbwS[64];        // 0.25 KB   (total ~73 KB)

  const int tid = threadIdx.x;
  const int wave = tid >> 6, lane = tid & 63;
  const long b0 = (long)blockIdx.x * BR;
  u16* xh0 = xhA;
  u16* xh1 = xhA + 16*RP;
  u16* xh2 = xhA + 32*RP;

  const u16* wsE0 = wsw;
  const u16* wsE1 = wsw + 1*131072;
  const u16* wsE2 = wsw + 2*131072;
  const u16* wsD0 = wsw + 3*131072;
  const u16* wsD1 = wsw + 4*131072;
  const u16* wsD2 = wsw + 5*131072;

  // persistent per-lane c-state: (row kgrp*4+(lane&3), units U0/U1), 3 layers
  float c0a=0.f,c0b=0.f, c1a=0.f,c1b=0.f, c2a=0.f,c2b=0.f;

  // src(0) prefetch
  float sA = 0.f, sB = 0.f;
  { int kk = tid & 255;
    if (kk < Dn){ int r0 = tid >> 8;
      sA = src[((size_t)(b0+r0)*Tn + 0)*Dn + kk];
      sB = src[((size_t)(b0+r0+4)*Tn + 0)*Dn + kk]; } }

  // ---- init LDS ----
  for (int i=tid; i<8192; i+=NTH) fwtS[i] = fwt[i];
  for (int i=tid; i<6*G4; i+=NTH) biasS[i] = bias[i];
  if (tid < 64) fbwS[tid] = fbw[tid];
  for (int i=tid; i<3*16*RP; i+=NTH) xhA[i] = 0;   // pads stay 0 forever
  __syncthreads();
  { int kk = tid & 255;
    if (kk < Dn){ int r0 = tid >> 8;
      wr_xh(xh0, r0,   kk, sA);
      wr_xh(xh0, r0+4, kk, sB); } }                // src(0) -> xh0.x
  __syncthreads();

  // ---------------- encoder: 3 barriers per t ----------------
  for (int t=0;t<Tn;t++){
    int tn = (t < Tn-1) ? t+1 : Tn-1;
    { int kk = tid & 255;                          // src(t+1) -> regs
      if (kk < Dn){ int r0 = tid >> 8;
        sA = src[((size_t)(b0+r0)*Tn + tn)*Dn + kk];
        sB = src[((size_t)(b0+r0+4)*Tn + tn)*Dn + kk]; } }
    layer_fused<6,false>(wsE0, biasS + 0*G4, xh0, xh0, Dn, xh1, h2S, c0a, c0b, wave, lane);
    // post-l0-barrier region: xh0.x has no readers until gemm_l0(t+1)
    if (t < Tn-1){ int kk = tid & 255;
      if (kk < Dn){ int r0 = tid >> 8;
        wr_xh(xh0, r0,   kk, sA);
        wr_xh(xh0, r0+4, kk, sB); } }
    layer_fused<8,false>(wsE1, biasS + 1*G4, xh1, xh1, Hn, xh2, h2S, c1a, c1b, wave, lane);
    layer_fused<8,false>(wsE2, biasS + 2*G4, xh2, xh2, Hn, (u16*)nullptr, h2S,
                         c2a, c2b, wave, lane);
  }

  // ---------------- decoder: 4 barriers per t ----------------
  // xh*.h-parts (written by enc t=99 epilogues) + c regs carry enc-final
  // state. Reset xh0.x to pred(-1)=0.
  { int r = tid >> 7, kk = tid & 127;
    if (kk < Dn){ xh0[r*RP + kk] = 0; xh0[(r+8)*RP + kk] = 0; } }
  bar_lds();

  for (int t=0;t<Tn;t++){
    layer_fused<6,false>(wsD0, biasS + 3*G4, xh0, xh0, Dn, xh1, h2S, c0a, c0b, wave, lane);
    layer_fused<8,false>(wsD1, biasS + 4*G4, xh1, xh1, Hn, xh2, h2S, c1a, c1b, wave, lane);
    layer_fused<8,true >(wsD2, biasS + 5*G4, xh2, xh2, Hn, (u16*)nullptr, h2S,
                         c2a, c2b, wave, lane);
    // post-l2-barrier region: h2S complete; xh2.h self-write runs in parallel
    proj_out(h2S, fwtS, fbwS, xh0, out, b0, t, tid);
    bar_lds();
  }
}

extern "C" void kernel_launch(void* const* d_in, const int* in_sizes, int n_in,
                              void* d_out, int out_size, void* d_ws, size_t ws_size,
                              hipStream_t stream)
{
  (void)in_sizes; (void)n_in; (void)out_size; (void)ws_size;
  const float* src = (const float*)d_in[0];
  WP p;
  for (int l=0;l<3;l++){
    p.W[l]    = (const float*)d_in[1  + 3*l];
    p.U[l]    = (const float*)d_in[2  + 3*l];
    p.Bb[l]   = (const float*)d_in[3  + 3*l];
    p.W[3+l]  = (const float*)d_in[10 + 3*l];
    p.U[3+l]  = (const float*)d_in[11 + 3*l];
    p.Bb[3+l] = (const float*)d_in[12 + 3*l];
  }
  p.fW = (const float*)d_in[19];
  p.fb = (const float*)d_in[20];

  // ws: wsw u16[786432] (1.5MB) | bias f32[3072] | fwt f32[8192] | fbw f32[64]
  u16*   wsw  = (u16*)d_ws;
  float* bias = (float*)((char*)d_ws + 6*131072*sizeof(u16));
  float* fwt  = bias + 6*512;
  float* fbw  = fwt + 8192;

  prep_kernel<<<(PREP_TOTAL + 255)/256, 256, 0, stream>>>(p, wsw, bias, fwt, fbw);
  lstm_kernel<<<NWG, NTH, 0, stream>>>(src, wsw, bias, fwt, fbw, (float*)d_out);
}

// Round 9
// 1918.074 us; speedup vs baseline: 1.8326x; 1.0787x over previous
//
#include <hip/hip_runtime.h>
#include <stdint.h>

#define Tn 100
#define Dn 51
#define Hn 128
#define G4 512     // 4*H
#define BR 8       // batch rows per workgroup
#define NWG 256    // workgroups (2048 / 8) = 1 WG/CU
#define NTH 1024   // 16 waves, 4/SIMD (proven R2 regime)
#define RP 264     // xhA row stride in bf16 elems (16B-aligned rows)
#define SLICE 16384 // u16 per staged K-slice (32 tiles x 1KB)

typedef unsigned int uint32;
typedef unsigned short u16;
typedef short s16x8 __attribute__((ext_vector_type(8)));   // 8 bf16 = 4 VGPRs
typedef float f32x4v __attribute__((ext_vector_type(4)));

__device__ __forceinline__ float rcp_(float x){ return __builtin_amdgcn_rcpf(x); }
__device__ __forceinline__ float sigm(float x){ return rcp_(1.f + __expf(-x)); }
__device__ __forceinline__ float tanh_(float x){ return 1.f - 2.f*rcp_(1.f + __expf(2.f*x)); }

// fp32 -> bf16 round-to-nearest-even
__device__ __forceinline__ u16 f2bf(float f){
  uint32 u = __float_as_uint(f);
  return (u16)((u + 0x7fffu + ((u >> 16) & 1u)) >> 16);
}
__device__ __forceinline__ float bf2f(u16 u){ return __uint_as_float(((uint32)u)<<16); }

// A-fragment trick: row r (0..7) = bf16-hi of xh row r; row r+8 = bf16-lo.
// One MFMA computes both pumps; epilogue sums D[r] + D[r+8] via shfl.
__device__ __forceinline__ void wr_xh(u16* __restrict__ xhA, int r, int k, float v){
  u16 h = f2bf(v);
  xhA[r*RP + k]     = h;
  xhA[(r+8)*RP + k] = f2bf(v - bf2f(h));
}

struct WP {
  const float* W[6];   // [4H, din]  enc0..2, dec0..2 (fp32)
  const float* U[6];   // [4H, H]
  const float* Bb[6];  // [4H]
  const float* fW;     // [D, H]
  const float* fb;     // [D]
};

// wsw = MFMA-B-fragment-swizzled bf16 weights, R2's PLAIN column layout.
// Per layer (131072 u16): chunk (n,s) at ((n*8+s)*64+lane)*8+j holding
// Wc[k = s*32+(lane>>4)*8+j][c = n*16+(lane&15)], Wc = [Wih | Whh] along k,
// zero-padded. Chunk (n,s) = contiguous 1KB = one global_load_lds batch.
// fwt: [128][52] f32 (k-major, 52-col pad; d>=51 zero). 52 cols -> proj lanes
// read consecutive floats, <=2 lanes/bank (free), and saves 5.4 KB vs [128][64].
#define FWTE (128*52)
#define PREP_TOTAL (6*131072 + 6*512 + FWTE + 64)
__global__ void prep_kernel(WP p, u16* __restrict__ wsw, float* __restrict__ bias,
                            float* __restrict__ fwt, float* __restrict__ fbw)
{
  int gid = blockIdx.x*256 + threadIdx.x;
  if (gid >= PREP_TOTAL) return;
  if (gid < 6*131072){
    int l = gid >> 17;
    int e = gid & 131071;
    int n    = e >> 12;
    int s    = (e >> 9) & 7;
    int lane = (e >> 3) & 63;
    int j    = e & 7;
    int k = s*32 + (lane >> 4)*8 + j;
    int c = n*16 + (lane & 15);
    int din = (l % 3 == 0) ? Dn : Hn;
    int K = din + Hn;
    u16 v = 0;
    if (k < K){
      float f = (k < din) ? p.W[l][(size_t)c*din + k] : p.U[l][(size_t)c*Hn + (k - din)];
      v = f2bf(f);
    }
    wsw[gid] = v;
  } else if (gid < 6*131072 + 6*512){
    int i = gid - 6*131072;
    bias[i] = p.Bb[i>>9][i & 511];
  } else if (gid < 6*131072 + 6*512 + FWTE){
    int i = gid - (6*131072 + 6*512);
    int k = i / 52, d = i % 52;
    fwt[i] = (d < Dn) ? p.fW[(size_t)d*Hn + k] : 0.f;
  } else {
    int d = gid - (6*131072 + 6*512 + FWTE);
    fbw[d] = (d < Dn) ? p.fb[d] : 0.f;
  }
}

// One 16B-per-lane async global->LDS batch = one (tile n, slice ts) 1KB chunk.
// LDS dest is wave-uniform base + lane*16 (m104); source is per-lane.
// Consumes ZERO VGPRs -- immune to the R1/R7/R11 64-VGPR spill cliff.
__device__ __forceinline__ void dma_tile(const u16* __restrict__ ws, u16* __restrict__ dslot,
                                         int n, int ts, int lane){
  const u16* g = ws + (((size_t)(n*8 + ts)) << 9) + (lane << 3);
  u16* l = dslot + (n << 9);
  __builtin_amdgcn_global_load_lds((const __attribute__((address_space(1))) uint32*)g,
                                   (__attribute__((address_space(3))) uint32*)l, 16, 0, 0);
}

// Barriers: gemm-end needs only DS drain (gates writes). act-end additionally
// drains vmcnt(0): the stage DMAs issued at act START land here (~1000 cy of
// act VALU in between -> the drain is ~free; this is m97's proven issue-early/
// drain-at-barrier discipline, NOT R5/R6's failed per-sub-phase counted vmcnt).
__device__ __forceinline__ void bar_lds(){
  asm volatile("s_waitcnt lgkmcnt(0)" ::: "memory");
  __builtin_amdgcn_s_barrier();
}
__device__ __forceinline__ void bar_vm(){
  asm volatile("s_waitcnt vmcnt(0) lgkmcnt(0)" ::: "memory");
  __builtin_amdgcn_s_barrier();
}

// gates[r][c] = biasS[c] + sum_k xh[r][k]*Wc[k][c] via mfma_f32_16x16x32_bf16.
// Wave w owns N-tiles n0=2w, 2w+1. Slices 0,1 come from the LDS stage (DMA'd
// during the previous act phase -> no global latency at gemm start, ramp gone);
// slices 2..S-1 stream global->VGPR with the proven unroll-2 window (their
// first group's loads hoist above the s0/s1 MFMAs and hide under them).
// C/D: col=lane&15, row=(lane>>4)*4+reg (m89) -> rows in lanes 0-31, +8 in 32-63.
template<int S>
__device__ __forceinline__ void gemm_mfma(const u16* __restrict__ wsl,
                                          const float* __restrict__ blS,
                                          const u16* __restrict__ stage,
                                          const u16* __restrict__ xh_in,
                                          float* __restrict__ gates,
                                          int wave, int lane)
{
  const int mrow = lane & 15, kgrp = lane >> 4;
  const int n0 = wave*2;
  const u16* bp0 = wsl + n0*4096 + lane*8;
  const int aoff = mrow*RP + (kgrp << 3);
  const int boff = lane*8;
  f32x4v acc0 = {0.f,0.f,0.f,0.f}, acc1 = {0.f,0.f,0.f,0.f};
  // s = 0,1 from LDS stage (per-wave-private region, landed at act-end bar_vm)
  #pragma unroll
  for (int s=0; s<2; s++){
    const u16* sb = stage + s*SLICE;
    s16x8 a  = *(const s16x8*)(xh_in + aoff + s*32);
    s16x8 b0 = *(const s16x8*)(sb + ((n0    ) << 9) + boff);
    s16x8 b1 = *(const s16x8*)(sb + ((n0 + 1) << 9) + boff);
    acc0 = __builtin_amdgcn_mfma_f32_16x16x32_bf16(a, b0, acc0, 0, 0, 0);
    acc1 = __builtin_amdgcn_mfma_f32_16x16x32_bf16(a, b1, acc1, 0, 0, 0);
  }
  // s = 2..S-1 global (unroll 2: the 4-load window the compiler tolerates)
  #pragma unroll 2
  for (int s=2; s<S; s++){
    s16x8 a  = *(const s16x8*)(xh_in + aoff + s*32);
    s16x8 b0 = *(const s16x8*)(bp0 + s*512);
    s16x8 b1 = *(const s16x8*)(bp0 + 4096 + s*512);
    acc0 = __builtin_amdgcn_mfma_f32_16x16x32_bf16(a, b0, acc0, 0, 0, 0);
    acc1 = __builtin_amdgcn_mfma_f32_16x16x32_bf16(a, b1, acc1, 0, 0, 0);
  }
  // fold lo-product rows (A rows 8-15, lanes 32-63) into hi rows (lanes 0-31)
  #pragma unroll
  for (int v=0; v<4; v++){
    acc0[v] += __shfl_down(acc0[v], 32);
    acc1[v] += __shfl_down(acc1[v], 32);
  }
  if (kgrp < 2){
    int rb = kgrp*4;
    int c0g = n0*16 + mrow, c1g = c0g + 16;
    float bv0 = blS[c0g], bv1 = blS[c1g];
    #pragma unroll
    for (int v=0; v<4; v++){
      gates[(rb+v)*G4 + c0g] = acc0[v] + bv0;
      gates[(rb+v)*G4 + c1g] = acc1[v] + bv1;
    }
  }
}

// Fused activation + NEXT-layer stage DMA. The 4 dma_tile calls go FIRST so
// the 64 KB/CU weight stream flies during the whole act phase (formerly dead
// time); they're drained by the act-end bar_vm. c-state in registers (static
// thread->(r,j) map); h written straight into consumer A-tiles (R2-proven).
__device__ __forceinline__ void act_step(const float* __restrict__ gates, float& cref,
                                         u16* __restrict__ xh_self, int din_self,
                                         u16* __restrict__ xh_next,
                                         float* __restrict__ h2S,
                                         const u16* __restrict__ wsNext,
                                         u16* __restrict__ stage, int tid)
{
  {
    int wave = tid >> 6, lane = tid & 63, n0 = wave*2;
    dma_tile(wsNext, stage,         n0,     0, lane);
    dma_tile(wsNext, stage,         n0 + 1, 0, lane);
    dma_tile(wsNext, stage + SLICE, n0,     1, lane);
    dma_tile(wsNext, stage + SLICE, n0 + 1, 1, lane);
  }
  int r = tid >> 7, j = tid & 127;       // 1024 threads = 8 rows x 128
  const float* g = gates + r*G4;
  float ig = sigm (g[j]);
  float fg = sigm (g[j + Hn]);
  float gg = tanh_(g[j + 2*Hn]);
  float og = sigm (g[j + 3*Hn]);
  cref = fg*cref + ig*gg;
  float hv = og*tanh_(cref);
  wr_xh(xh_self, r, din_self + j, hv);
  if (xh_next) wr_xh(xh_next, r, j, hv);
  if (h2S)     h2S[r*Hn + j] = hv;
}

// OUTPUT IS FP32. 8 rows x 64 cols; lanes d>=52 idle. fwtS[k*52+d]: consecutive
// floats per k -> <=2 lanes/bank, conflict-free. pred feeds xh0.x directly.
__device__ __forceinline__ void proj_out(const float* __restrict__ h2S,
                                         const float* __restrict__ fwtS,
                                         const float* __restrict__ fbwS,
                                         u16* __restrict__ xh0,
                                         float* __restrict__ out, long b0, int t, int tid)
{
  if (tid < 512){
    int r = tid >> 6, d = tid & 63;
    const float* h = h2S + r*Hn;
    float acc = 0.f;
    if (d < 52){
      #pragma unroll 8
      for (int k=0;k<Hn;k++) acc += h[k] * fwtS[k*52 + d];
    }
    if (d < Dn){
      float pv = acc + fbwS[d];
      out[((size_t)(b0+r)*Tn + (Tn-1-t))*Dn + d] = pv;
      wr_xh(xh0, r, d, pv);
    }
  }
}

// (1024, 4): 4 waves/EU -> VGPR cap 128. Tripwires: VGPR>=64 + FETCH>>300MB =
// spill/DMA-anomaly -> revert to R2.
__global__ __launch_bounds__(NTH, 4) void lstm_kernel(
    const float* __restrict__ src, const u16* __restrict__ wsw,
    const float* __restrict__ bias, const float* __restrict__ fwt,
    const float* __restrict__ fbw, float* __restrict__ out)
{
  __shared__ __align__(16) u16   stage[2*SLICE];  // 64 KB next-gemm s0,s1 stage
  __shared__ __align__(16) u16   xhA[3*16*RP];    // 24.75 KB per-layer A-tiles
  __shared__ __align__(16) float gates[BR*G4];    // 16 KB
  __shared__ __align__(16) float fwtS[FWTE];      // 26 KB f32 [128][52]
  __shared__ __align__(16) float biasS[6*G4];     // 12 KB
  __shared__ __align__(16) float h2S[BR*Hn];      // 4 KB dec-l2 h for proj
  __shared__ __align__(16) float fbwS[64];        // 0.25 KB   (total ~147 KB)

  const int tid = threadIdx.x;
  const int wave = tid >> 6, lane = tid & 63;
  const long b0 = (long)blockIdx.x * BR;
  u16* xh0 = xhA;
  u16* xh1 = xhA + 16*RP;
  u16* xh2 = xhA + 32*RP;

  const u16* wsE0 = wsw;
  const u16* wsE1 = wsw + 1*131072;
  const u16* wsE2 = wsw + 2*131072;
  const u16* wsD0 = wsw + 3*131072;
  const u16* wsD1 = wsw + 4*131072;
  const u16* wsD2 = wsw + 5*131072;

  // persistent per-thread c-state (act mapping r=tid>>7, j=tid&127)
  float c0 = 0.f, c1 = 0.f, c2 = 0.f;

  // src(0) prefetch
  float sA = 0.f, sB = 0.f;
  { int kk = tid & 255;
    if (kk < Dn){ int r0 = tid >> 8;
      sA = src[((size_t)(b0+r0)*Tn + 0)*Dn + kk];
      sB = src[((size_t)(b0+r0+4)*Tn + 0)*Dn + kk]; } }

  // ---- init LDS ----
  for (int i=tid; i<FWTE; i+=NTH) fwtS[i] = fwt[i];
  for (int i=tid; i<6*G4; i+=NTH) biasS[i] = bias[i];
  if (tid < 64) fbwS[tid] = fbw[tid];
  for (int i=tid; i<3*16*RP; i+=NTH) xhA[i] = 0;   // pads stay 0 forever
  __syncthreads();
  { int kk = tid & 255;
    if (kk < Dn){ int r0 = tid >> 8;
      wr_xh(xh0, r0,   kk, sA);
      wr_xh(xh0, r0+4, kk, sB); } }                // src(0) -> xh0.x
  // prime stage with e0 slices 0,1
  { int n0 = wave*2;
    dma_tile(wsE0, stage,         n0,     0, lane);
    dma_tile(wsE0, stage,         n0 + 1, 0, lane);
    dma_tile(wsE0, stage + SLICE, n0,     1, lane);
    dma_tile(wsE0, stage + SLICE, n0 + 1, 1, lane);
  }
  __syncthreads();                                 // full drain: stage ready

  // ---------------- encoder: 6 phases per t ----------------
  for (int t=0;t<Tn;t++){
    int tn = (t < Tn-1) ? t+1 : Tn-1;
    { int kk = tid & 255;                          // src(t+1) -> regs
      if (kk < Dn){ int r0 = tid >> 8;
        sA = src[((size_t)(b0+r0)*Tn + tn)*Dn + kk];
        sB = src[((size_t)(b0+r0+4)*Tn + tn)*Dn + kk]; } }
    gemm_mfma<6>(wsE0, biasS + 0*G4, stage, xh0, gates, wave, lane);
    bar_lds();
    act_step(gates, c0, xh0, Dn, xh1, nullptr, wsE1, stage, tid);
    if (t < Tn-1){ int kk = tid & 255;             // xh0.x idle during act-l0
      if (kk < Dn){ int r0 = tid >> 8;
        wr_xh(xh0, r0,   kk, sA);
        wr_xh(xh0, r0+4, kk, sB); } }
    bar_vm();

    gemm_mfma<8>(wsE1, biasS + 1*G4, stage, xh1, gates, wave, lane);
    bar_lds();
    act_step(gates, c1, xh1, Hn, xh2, nullptr, wsE2, stage, tid);
    bar_vm();

    gemm_mfma<8>(wsE2, biasS + 2*G4, stage, xh2, gates, wave, lane);
    bar_lds();
    act_step(gates, c2, xh2, Hn, nullptr, nullptr,
             (t < Tn-1) ? wsE0 : wsD0, stage, tid);
    bar_vm();
  }

  // ---------------- decoder: 7 phases per t ----------------
  // xh*.h-parts + c regs carry enc-final state. Reset xh0.x to pred(-1)=0.
  { int r = tid >> 7, kk = tid & 127;
    if (kk < Dn){ xh0[r*RP + kk] = 0; xh0[(r+8)*RP + kk] = 0; } }
  bar_lds();

  for (int t=0;t<Tn;t++){
    gemm_mfma<6>(wsD0, biasS + 3*G4, stage, xh0, gates, wave, lane);
    bar_lds();
    act_step(gates, c0, xh0, Dn, xh1, nullptr, wsD1, stage, tid);
    bar_vm();

    gemm_mfma<8>(wsD1, biasS + 4*G4, stage, xh1, gates, wave, lane);
    bar_lds();
    act_step(gates, c1, xh1, Hn, xh2, nullptr, wsD2, stage, tid);
    bar_vm();

    gemm_mfma<8>(wsD2, biasS + 5*G4, stage, xh2, gates, wave, lane);
    bar_lds();
    // stages d0 for t+1 (redundant at t=99: harmless 64 KB L2 re-read)
    act_step(gates, c2, xh2, Hn, nullptr, h2S, wsD0, stage, tid);
    bar_vm();

    proj_out(h2S, fwtS, fbwS, xh0, out, b0, t, tid);
    bar_lds();
  }
}

extern "C" void kernel_launch(void* const* d_in, const int* in_sizes, int n_in,
                              void* d_out, int out_size, void* d_ws, size_t ws_size,
                              hipStream_t stream)
{
  (void)in_sizes; (void)n_in; (void)out_size; (void)ws_size;
  const float* src = (const float*)d_in[0];
  WP p;
  for (int l=0;l<3;l++){
    p.W[l]    = (const float*)d_in[1  + 3*l];
    p.U[l]    = (const float*)d_in[2  + 3*l];
    p.Bb[l]   = (const float*)d_in[3  + 3*l];
    p.W[3+l]  = (const float*)d_in[10 + 3*l];
    p.U[3+l]  = (const float*)d_in[11 + 3*l];
    p.Bb[3+l] = (const float*)d_in[12 + 3*l];
  }
  p.fW = (const float*)d_in[19];
  p.fb = (const float*)d_in[20];

  // ws: wsw u16[786432] (1.5MB) | bias f32[3072] | fwt f32[6656] | fbw f32[64]
  u16*   wsw  = (u16*)d_ws;
  float* bias = (float*)((char*)d_ws + 6*131072*sizeof(u16));
  float* fwt  = bias + 6*512;
  float* fbw  = fwt + FWTE;

  prep_kernel<<<(PREP_TOTAL + 255)/256, 256, 0, stream>>>(p, wsw, bias, fwt, fbw);
  lstm_kernel<<<NWG, NTH, 0, stream>>>(src, wsw, bias, fwt, fbw, (float*)d_out);
}